// Round 1
// baseline (1488.957 us; speedup 1.0000x reference)
//
#include <hip/hip_runtime.h>
#include <math.h>

// Problem constants (fixed by the reference)
#define N_   16
#define CIN  16
#define D_   32
#define H_   64
#define W_   64
#define COUT 32
#define DP_  16   // pooled depth
#define HP_  32   // pooled height
#define WP_  32   // pooled width

// Block: 256 threads = 32 oc (lane low bits) x 8 pooled-w (wq).
// Grid: (4 w-tiles of 8 pooled-w, 32 hp, 16 n); dp in [0,16) looped inside
// so the 55 KB weight staging is amortized over 16 dp steps.
//
// LDS: weights transposed [ick][oc] (conflict-free inner reads: lanes 0..31
// read consecutive oc -> banks 0..31), input patch [ic][d4][h4][w18].
__global__ __launch_bounds__(256, 2)
void fused_conv_pool_lse(const float* __restrict__ x,
                         const float* __restrict__ w,
                         const float* __restrict__ bias,
                         float* __restrict__ out) {
  __shared__ float wlds[COUT * CIN * 27];   // 13824 floats, [ick*32 + oc]
  __shared__ float plds[CIN * 4 * 4 * 18];  // 4608 floats,  [((ic*4+d)*4+h)*18 + w]

  const int tx = threadIdx.x;
  const int oc = tx & 31;
  const int wq = tx >> 5;          // 0..7 pooled-w within tile
  const int wtile = blockIdx.x;    // 0..3
  const int hp = blockIdx.y;       // 0..31
  const int n  = blockIdx.z;       // 0..15

  // ---- stage weights (once per block), transposed to [ick][oc] ----
  for (int i = tx; i < COUT * CIN * 27; i += 256) {
    int o = i / 432;               // 432 = CIN*27
    int ick = i - o * 432;
    wlds[ick * 32 + o] = w[i];
  }

  const float bv = bias[oc];
  const int h0 = 2 * hp - 1;
  const int w0 = 16 * wtile - 1;
  const int pwoff = 2 * wq;

  for (int dp = 0; dp < DP_; ++dp) {
    const int d0 = 2 * dp - 1;
    __syncthreads();  // weights ready (iter 0); prior compute done (iter >0)

    // ---- stage input patch: 16 ic x 4d x 4h x 18w ----
    for (int i = tx; i < CIN * 4 * 4 * 18; i += 256) {
      int ww = i % 18;
      int t = i / 18;
      int h = t & 3; t >>= 2;
      int d = t & 3;
      int ic = t >> 2;
      int gd = d0 + d, gh = h0 + h, gw = w0 + ww;
      float v = 0.f;
      if ((unsigned)gd < (unsigned)D_ && (unsigned)gh < (unsigned)H_ &&
          (unsigned)gw < (unsigned)W_)
        v = x[(((n * CIN + ic) * D_ + gd) * H_ + gh) * W_ + gw];
      plds[i] = v;
    }
    __syncthreads();

    // ---- conv for the 2x2x2 window of this thread's pooled output ----
    float acc[2][2][2] = {};
    for (int ic = 0; ic < CIN; ++ic) {
      float rv[4][4][4];
      const float* pb = &plds[ic * 288 + pwoff];  // 288 = 4*4*18
      #pragma unroll
      for (int d = 0; d < 4; ++d) {
        #pragma unroll
        for (int h = 0; h < 4; ++h) {
          // 8B-aligned (all index terms even): ds_read_b64 pairs
          const float2* p2 = (const float2*)(pb + (d * 4 + h) * 18);
          float2 a = p2[0], b = p2[1];
          rv[d][h][0] = a.x; rv[d][h][1] = a.y;
          rv[d][h][2] = b.x; rv[d][h][3] = b.y;
        }
      }
      const float* wb = &wlds[ic * 27 * 32 + oc];
      #pragma unroll
      for (int kd = 0; kd < 3; ++kd)
        #pragma unroll
        for (int kh = 0; kh < 3; ++kh)
          #pragma unroll
          for (int kw = 0; kw < 3; ++kw) {
            float wv = wb[((kd * 3 + kh) * 3 + kw) * 32];
            #pragma unroll
            for (int pd = 0; pd < 2; ++pd)
              #pragma unroll
              for (int ph = 0; ph < 2; ++ph)
                #pragma unroll
                for (int pw = 0; pw < 2; ++pw)
                  acc[pd][ph][pw] =
                      fmaf(wv, rv[pd + kd][ph + kh][pw + kw], acc[pd][ph][pw]);
          }
    }

    // ---- 2x2x2 max pool (+bias commutes with max) ----
    float m = acc[0][0][0];
    m = fmaxf(m, acc[0][0][1]);
    m = fmaxf(m, acc[0][1][0]);
    m = fmaxf(m, acc[0][1][1]);
    m = fmaxf(m, acc[1][0][0]);
    m = fmaxf(m, acc[1][0][1]);
    m = fmaxf(m, acc[1][1][0]);
    m = fmaxf(m, acc[1][1][1]);
    float v = m + bv;

    // ---- logsumexp over 32 oc: lanes 0..31 / 32..63 hold oc 0..31 ----
    float M = v;
    #pragma unroll
    for (int s = 16; s >= 1; s >>= 1) M = fmaxf(M, __shfl_xor(M, s, 64));
    float e = expf(v - M);
    float S = e;
    #pragma unroll
    for (int s = 16; s >= 1; s >>= 1) S += __shfl_xor(S, s, 64);

    if (oc == 0) {
      float r = M + logf(S);
      int wp = wtile * 8 + wq;
      out[((n * DP_ + dp) * HP_ + hp) * WP_ + wp] = fmaxf(r, 0.f);
    }
  }
}

extern "C" void kernel_launch(void* const* d_in, const int* in_sizes, int n_in,
                              void* d_out, int out_size, void* d_ws, size_t ws_size,
                              hipStream_t stream) {
  const float* x = (const float*)d_in[0];
  const float* w = (const float*)d_in[1];
  const float* b = (const float*)d_in[2];
  float* out = (float*)d_out;
  dim3 grid(4, 32, 16);
  fused_conv_pool_lse<<<grid, dim3(256), 0, stream>>>(x, w, b, out);
}

// Round 2
// 285.501 us; speedup vs baseline: 5.2152x; 5.2152x over previous
//
#include <hip/hip_runtime.h>
#include <hip/hip_bf16.h>
#include <math.h>

#define N_   16
#define CIN  16
#define D_   32
#define H_   64
#define W_   64
#define COUT 32

using frag  = __attribute__((ext_vector_type(8))) short;   // 8 bf16 = 4 VGPRs
using v16f  = __attribute__((ext_vector_type(16))) float;  // MFMA 32x32 accum

static __device__ __forceinline__ unsigned short f2bf(float f) {
  union { float f; unsigned u; } a; a.f = f;
  unsigned u = a.u;
  unsigned r = (u + 0x7fffu + ((u >> 16) & 1u)) >> 16;   // RNE
  return (unsigned short)r;
}
static __device__ __forceinline__ unsigned pack2(float lo, float hi) {
  return (unsigned)f2bf(lo) | ((unsigned)f2bf(hi) << 16);
}

// ---------------- Pass 1: x[n][ic][d][h][w] fp32 -> xT[n][d][h][w][ic] bf16 ----
// One wave per (n,d,h) row: lanes = w. All loads & stores coalesced.
__global__ __launch_bounds__(256)
void transpose_x(const float* __restrict__ x, __hip_bfloat16* __restrict__ xT) {
  int wave = blockIdx.x * 4 + (threadIdx.x >> 6);
  int lane = threadIdx.x & 63;
  int h = wave & 63;
  int t = wave >> 6;
  int d = t & 31;
  int n = t >> 5;
  const float* xp = x + ((n * CIN) * D_ + d) * (H_ * W_) + h * W_ + lane;
  __hip_bfloat16* op = xT + ((((n * D_ + d) * H_ + h) * W_) + lane) * CIN;
  #pragma unroll
  for (int half = 0; half < 2; ++half) {
    float v[8];
    #pragma unroll
    for (int j = 0; j < 8; ++j) v[j] = xp[(half * 8 + j) * (D_ * H_ * W_)];
    uint4 val;
    val.x = pack2(v[0], v[1]); val.y = pack2(v[2], v[3]);
    val.z = pack2(v[4], v[5]); val.w = pack2(v[6], v[7]);
    *(uint4*)(op + half * 8) = val;
  }
}

// ---------------- Pass 2: MFMA implicit-GEMM conv + pool + LSE + relu ---------
// Block = 256 thr = 4 waves. Grid (wt=2, hpt=8, z=32: n=z>>1, dphalf=z&1).
// Wave q computes h-pair hp=4*hpt+q, both conv-d rows of dp, 32 conv-w.
// xlds[p=4][hr=10][w=34][ic=16] bf16 (rows = 32 B, ic contiguous).
// wlds[tap=27][oc=32][ic=16] bf16.
__global__ __launch_bounds__(256, 2)
void conv_mfma(const __hip_bfloat16* __restrict__ xT,
               const float* __restrict__ w,
               const float* __restrict__ bias,
               float* __restrict__ out) {
  __shared__ __hip_bfloat16 xlds[4 * 10 * 34 * 16];   // 43520 B
  __shared__ __hip_bfloat16 wlds[27 * 32 * 16];       // 27648 B

  const int tid = threadIdx.x;
  const int lane = tid & 63;
  const int q = tid >> 6;            // wave id
  const int m = lane & 31;
  const int hs = lane >> 5;
  const int wt = blockIdx.x;         // 0..1
  const int hpt = blockIdx.y;        // 0..7
  const int n = blockIdx.z >> 1;
  const int dphalf = blockIdx.z & 1;

  // ---- stage weights (once per block): wlds[tap][oc][ic] <- w[oc][ic][tap] ----
  for (int i = tid; i < 27 * 32 * 16; i += 256) {
    int ic = i & 15;
    int t = i >> 4;
    int oc = t & 31;
    int tap = t >> 5;
    wlds[i] = __hip_bfloat16(__hip_bfloat16_raw{f2bf(w[(oc * 16 + ic) * 27 + tap])});
  }

  const float bv = bias[m];
  const int abase = m * 16 + hs * 8;

  for (int dpi = 0; dpi < 8; ++dpi) {
    const int dp = dphalf * 8 + dpi;
    __syncthreads();   // previous compute done before overwriting xlds

    // ---- stage x tile: wave q stages plane p=q, rows hr=0..9 ----
    {
      const int d = 2 * dp - 1 + q;
      for (int rr = 0; rr < 10; ++rr) {
        const int h = 8 * hpt - 1 + rr;
        __hip_bfloat16* ldsrow = &xlds[(q * 10 + rr) * 34 * 16];  // w-slot 0
        const bool valid = ((unsigned)d < (unsigned)D_) && ((unsigned)h < (unsigned)H_);
        if (valid) {
          const __hip_bfloat16* g =
              xT + (((n * D_ + d) * H_ + h) * W_ + wt * 32) * CIN;
          // main body: w-slots 1..32  (1024 B, lane*16B)
          __builtin_amdgcn_global_load_lds(
              (const __attribute__((address_space(1))) void*)(g + lane * 8),
              (__attribute__((address_space(3))) void*)(ldsrow + 16),
              16, 0, 0);
          // halo: w-slot 0 (gw = wt*32-1) and w-slot 33 (gw = wt*32+32)
          if (lane < 16) {
            int side = lane >> 3;          // 0 left, 1 right
            int j = lane & 7;              // dword within 32B row
            int gw = side ? (wt * 32 + 32) : (wt * 32 - 1);
            int slot = side ? 33 : 0;
            unsigned v = 0;
            if ((unsigned)gw < (unsigned)W_)
              v = *(const unsigned*)(xT + (((n * D_ + d) * H_ + h) * W_ + gw) * CIN + j * 2);
            *(unsigned*)((char*)ldsrow + slot * 32 + j * 4) = v;
          }
        } else {
          unsigned* zp = (unsigned*)ldsrow;
          for (int k2 = lane; k2 < 34 * 8; k2 += 64) zp[k2] = 0;
        }
      }
    }
    __syncthreads();   // staging visible (incl. global_load_lds drain)

    // ---- 108 MFMAs: acc[td][th] = 32w x 32oc tiles ----
    v16f acc[2][2];
    #pragma unroll
    for (int td = 0; td < 2; ++td)
      #pragma unroll
      for (int th = 0; th < 2; ++th)
        #pragma unroll
        for (int e = 0; e < 16; ++e) acc[td][th][e] = 0.f;

    #pragma unroll
    for (int kw = 0; kw < 3; ++kw) {
      #pragma unroll
      for (int kd = 0; kd < 3; ++kd) {
        frag a[2][2];   // [pi = td][slot = s&1], s = th+kh (x h-row = 2q+s)
        a[0][0] = *(const frag*)&xlds[(((kd + 0) * 10 + 2 * q + 0) * 34 + kw) * 16 + abase];
        a[1][0] = *(const frag*)&xlds[(((kd + 1) * 10 + 2 * q + 0) * 34 + kw) * 16 + abase];
        a[0][1] = *(const frag*)&xlds[(((kd + 0) * 10 + 2 * q + 1) * 34 + kw) * 16 + abase];
        a[1][1] = *(const frag*)&xlds[(((kd + 1) * 10 + 2 * q + 1) * 34 + kw) * 16 + abase];
        #pragma unroll
        for (int kh = 0; kh < 3; ++kh) {
          frag b = *(const frag*)&wlds[((kd * 3 + kh) * 3 + kw) * 512 + abase];
          if (kh > 0) {
            const int s = kh + 1;   // new row for th=1
            a[0][s & 1] = *(const frag*)&xlds[(((kd + 0) * 10 + 2 * q + s) * 34 + kw) * 16 + abase];
            a[1][s & 1] = *(const frag*)&xlds[(((kd + 1) * 10 + 2 * q + s) * 34 + kw) * 16 + abase];
          }
          #pragma unroll
          for (int td = 0; td < 2; ++td)
            #pragma unroll
            for (int th = 0; th < 2; ++th) {
              const int s = kh + th;
              acc[td][th] = __builtin_amdgcn_mfma_f32_32x32x16_bf16(
                  a[td][s & 1], b, acc[td][th], 0, 0, 0);
            }
        }
      }
    }

    // ---- pool (2x2x2) + bias + LSE over oc + relu + store ----
    #pragma unroll
    for (int j = 0; j < 8; ++j) {
      float p0 = fmaxf(fmaxf(acc[0][0][2 * j], acc[0][0][2 * j + 1]),
                       fmaxf(acc[0][1][2 * j], acc[0][1][2 * j + 1]));
      float p1 = fmaxf(fmaxf(acc[1][0][2 * j], acc[1][0][2 * j + 1]),
                       fmaxf(acc[1][1][2 * j], acc[1][1][2 * j + 1]));
      float v = fmaxf(p0, p1) + bv;
      float M = v;
      #pragma unroll
      for (int s = 16; s >= 1; s >>= 1) M = fmaxf(M, __shfl_xor(M, s, 64));
      float S = __expf(v - M);
      #pragma unroll
      for (int s = 16; s >= 1; s >>= 1) S += __shfl_xor(S, s, 64);
      if (m == 0) {
        float r = fmaxf(M + __logf(S), 0.f);
        int pw = 16 * wt + (j & 1) + 4 * (j >> 1) + 2 * hs;
        out[((n * 16 + dp) * 32 + 4 * hpt + q) * 32 + pw] = r;
      }
    }
  }
}

// ---------------- Fallback (fp32 direct, known-correct) -----------------------
__global__ __launch_bounds__(256, 2)
void fused_conv_pool_lse(const float* __restrict__ x,
                         const float* __restrict__ w,
                         const float* __restrict__ bias,
                         float* __restrict__ out) {
  __shared__ float wl[COUT * CIN * 27];
  __shared__ float pl[CIN * 4 * 4 * 18];
  const int tx = threadIdx.x;
  const int oc = tx & 31, wq = tx >> 5;
  const int wtile = blockIdx.x, hp = blockIdx.y, n = blockIdx.z;
  for (int i = tx; i < COUT * CIN * 27; i += 256) {
    int o = i / 432, ick = i - o * 432;
    wl[ick * 32 + o] = w[i];
  }
  const float bv = bias[oc];
  const int h0 = 2 * hp - 1, w0 = 16 * wtile - 1, pwoff = 2 * wq;
  for (int dp = 0; dp < 16; ++dp) {
    const int d0 = 2 * dp - 1;
    __syncthreads();
    for (int i = tx; i < CIN * 4 * 4 * 18; i += 256) {
      int ww = i % 18, t = i / 18;
      int h = t & 3; t >>= 2;
      int d = t & 3, ic = t >> 2;
      int gd = d0 + d, gh = h0 + h, gw = w0 + ww;
      float v = 0.f;
      if ((unsigned)gd < (unsigned)D_ && (unsigned)gh < (unsigned)H_ &&
          (unsigned)gw < (unsigned)W_)
        v = x[(((n * CIN + ic) * D_ + gd) * H_ + gh) * W_ + gw];
      pl[i] = v;
    }
    __syncthreads();
    float acc[2][2][2] = {};
    for (int ic = 0; ic < CIN; ++ic) {
      float rv[4][4][4];
      const float* pb = &pl[ic * 288 + pwoff];
      #pragma unroll
      for (int d = 0; d < 4; ++d)
        #pragma unroll
        for (int h = 0; h < 4; ++h) {
          const float2* p2 = (const float2*)(pb + (d * 4 + h) * 18);
          float2 a = p2[0], b2 = p2[1];
          rv[d][h][0] = a.x; rv[d][h][1] = a.y;
          rv[d][h][2] = b2.x; rv[d][h][3] = b2.y;
        }
      const float* wb = &wl[ic * 27 * 32 + oc];
      #pragma unroll
      for (int kd = 0; kd < 3; ++kd)
        #pragma unroll
        for (int kh = 0; kh < 3; ++kh)
          #pragma unroll
          for (int kw = 0; kw < 3; ++kw) {
            float wv = wb[((kd * 3 + kh) * 3 + kw) * 32];
            #pragma unroll
            for (int pd = 0; pd < 2; ++pd)
              #pragma unroll
              for (int ph = 0; ph < 2; ++ph)
                #pragma unroll
                for (int pw = 0; pw < 2; ++pw)
                  acc[pd][ph][pw] = fmaf(wv, rv[pd + kd][ph + kh][pw + kw], acc[pd][ph][pw]);
          }
    }
    float mx = acc[0][0][0];
    mx = fmaxf(mx, acc[0][0][1]); mx = fmaxf(mx, acc[0][1][0]);
    mx = fmaxf(mx, acc[0][1][1]); mx = fmaxf(mx, acc[1][0][0]);
    mx = fmaxf(mx, acc[1][0][1]); mx = fmaxf(mx, acc[1][1][0]);
    mx = fmaxf(mx, acc[1][1][1]);
    float v = mx + bv;
    float M = v;
    #pragma unroll
    for (int s = 16; s >= 1; s >>= 1) M = fmaxf(M, __shfl_xor(M, s, 64));
    float S = __expf(v - M);
    #pragma unroll
    for (int s = 16; s >= 1; s >>= 1) S += __shfl_xor(S, s, 64);
    if (oc == 0) {
      float r = M + __logf(S);
      out[((n * 16 + dp) * 32 + hp) * 32 + wtile * 8 + wq] = fmaxf(r, 0.f);
    }
  }
}

extern "C" void kernel_launch(void* const* d_in, const int* in_sizes, int n_in,
                              void* d_out, int out_size, void* d_ws, size_t ws_size,
                              hipStream_t stream) {
  const float* x = (const float*)d_in[0];
  const float* w = (const float*)d_in[1];
  const float* b = (const float*)d_in[2];
  float* out = (float*)d_out;
  const size_t need = (size_t)N_ * D_ * H_ * W_ * CIN * 2;  // 64 MiB
  if (ws_size >= need) {
    __hip_bfloat16* xT = (__hip_bfloat16*)d_ws;
    transpose_x<<<dim3(8192), dim3(256), 0, stream>>>(x, xT);
    conv_mfma<<<dim3(2, 8, 32), dim3(256), 0, stream>>>(xT, w, b, out);
  } else {
    fused_conv_pool_lse<<<dim3(4, 32, 16), dim3(256), 0, stream>>>(x, w, b, out);
  }
}

// Round 3
// 269.228 us; speedup vs baseline: 5.5305x; 1.0604x over previous
//
#include <hip/hip_runtime.h>
#include <hip/hip_bf16.h>
#include <math.h>

#define N_   16
#define CIN  16
#define D_   32
#define H_   64
#define W_   64
#define COUT 32

using frag  = __attribute__((ext_vector_type(8))) short;   // 8 bf16 = 4 VGPRs
using v16f  = __attribute__((ext_vector_type(16))) float;  // MFMA 32x32 accum

static __device__ __forceinline__ unsigned short f2bf(float f) {
  union { float f; unsigned u; } a; a.f = f;
  unsigned u = a.u;
  unsigned r = (u + 0x7fffu + ((u >> 16) & 1u)) >> 16;   // RNE
  return (unsigned short)r;
}
static __device__ __forceinline__ unsigned pack2(float lo, float hi) {
  return (unsigned)f2bf(lo) | ((unsigned)f2bf(hi) << 16);
}

// ---- Pass 1a: x[n][ic][d][h][w] fp32 -> xT[n][d][h][w][ic] bf16 --------------
// lane -> (w = lane>>1, ic-half = lane&1). Store: lane writes 16 B at byte
// offset lane*16 -> one fully dense 1 KiB store per wave. Loads: per j, two
// 128 B segments (ic differs only with lane parity).
__global__ __launch_bounds__(256)
void transpose_x(const float* __restrict__ x, __hip_bfloat16* __restrict__ xT) {
  int wid = blockIdx.x * 4 + (threadIdx.x >> 6);   // 65536 waves total
  int lane = threadIdx.x & 63;
  int wl = lane >> 1, half = lane & 1;
  int wh = wid & 1;
  int h = (wid >> 1) & 63;
  int d = (wid >> 7) & 31;
  int n = wid >> 12;
  int w = wh * 32 + wl;
  const float* xp = x + (((size_t)(n * CIN + half * 8) * D_ + d) * H_ + h) * W_ + w;
  float v[8];
  #pragma unroll
  for (int j = 0; j < 8; ++j) v[j] = xp[(size_t)j * (D_ * H_ * W_)];
  uint4 val;
  val.x = pack2(v[0], v[1]); val.y = pack2(v[2], v[3]);
  val.z = pack2(v[4], v[5]); val.w = pack2(v[6], v[7]);
  *(uint4*)(xT + ((((size_t)(n * D_ + d) * H_ + h) * W_) + w) * CIN + half * 8) = val;
}

// ---- Pass 1b: weights fp32 [oc][ic][tap] -> bf16 [tap][oc][ic] ---------------
__global__ __launch_bounds__(256)
void prep_w(const float* __restrict__ w, __hip_bfloat16* __restrict__ wT) {
  int i = blockIdx.x * 256 + threadIdx.x;
  if (i >= 27 * 32 * 16) return;
  int ic = i & 15, t = i >> 4, oc = t & 31, tap = t >> 5;
  wT[i] = __hip_bfloat16(__hip_bfloat16_raw{f2bf(w[(oc * 16 + ic) * 27 + tap])});
}

// ---- Pass 2: MFMA implicit-GEMM conv + pool + LSE + relu ---------------------
// Block = 4 waves. Grid (wt=2, hpt=8, z=32: n=z>>1, dphalf=z&1).
// xlds: ring of 4 d-planes (slot = plane&3) x 10 h-rows x 34 w x 16 ic.
// After dp warm-up only 2 new planes staged per iteration.
__global__ __launch_bounds__(256, 2)
void conv_mfma(const __hip_bfloat16* __restrict__ xT,
               const __hip_bfloat16* __restrict__ wT,
               const float* __restrict__ bias,
               float* __restrict__ out) {
  __shared__ __hip_bfloat16 xlds[4 * 10 * 34 * 16];   // 43520 B
  __shared__ __hip_bfloat16 wlds[27 * 32 * 16];       // 27648 B

  const int tid = threadIdx.x;
  const int lane = tid & 63;
  const int q = tid >> 6;            // wave id
  const int m = lane & 31;
  const int hs = lane >> 5;
  const int wt = blockIdx.x;         // 0..1
  const int hpt = blockIdx.y;        // 0..7
  const int n = blockIdx.z >> 1;
  const int dphalf = blockIdx.z & 1;

  // stage weights: dense uint4 copy of pre-converted bf16 [tap][oc][ic]
  {
    const uint4* src = (const uint4*)wT;
    uint4* dst = (uint4*)wlds;
    for (int i = tid; i < 3456; i += 256) dst[i] = src[i];
  }

  const float bv = bias[m];
  const int abase = m * 16 + hs * 8;

  // stage rows [r0, r0+nr) of global d-plane g into ring slot g&3
  auto stage_rows = [&](int g, int r0, int nr) {
    const int s = g & 3;
    const bool vd = ((unsigned)g < (unsigned)D_);
    for (int rr = r0; rr < r0 + nr; ++rr) {
      const int h = 8 * hpt - 1 + rr;
      __hip_bfloat16* ldsrow = &xlds[(s * 10 + rr) * 34 * 16];
      if (vd && (unsigned)h < (unsigned)H_) {
        const __hip_bfloat16* gp =
            xT + (((size_t)(n * D_ + g) * H_ + h) * W_ + wt * 32) * CIN;
        __builtin_amdgcn_global_load_lds(
            (const __attribute__((address_space(1))) void*)(gp + lane * 8),
            (__attribute__((address_space(3))) void*)(ldsrow + 16), 16, 0, 0);
        if (lane < 16) {
          int side = lane >> 3, j = lane & 7;
          int gw = side ? (wt * 32 + 32) : (wt * 32 - 1);
          int slot = side ? 33 : 0;
          unsigned v = 0;
          if ((unsigned)gw < (unsigned)W_)
            v = *(const unsigned*)(xT +
                (((size_t)(n * D_ + g) * H_ + h) * W_ + gw) * CIN + j * 2);
          *(unsigned*)((char*)ldsrow + slot * 32 + j * 4) = v;
        }
      } else {
        unsigned* zp = (unsigned*)ldsrow;
        for (int k2 = lane; k2 < 34 * 8; k2 += 64) zp[k2] = 0;
      }
    }
  };

  for (int dpi = 0; dpi < 8; ++dpi) {
    const int dp = dphalf * 8 + dpi;
    __syncthreads();   // previous compute done before overwriting ring slots
    if (dpi == 0) {
      stage_rows(2 * dp - 1 + q, 0, 10);            // all 4 planes, 10 rows each
    } else {
      stage_rows(2 * dp + 1 + (q >> 1), 5 * (q & 1), 5);  // 2 new planes
    }
    __syncthreads();   // staging visible (vmcnt drain)

    v16f acc[2][2];
    #pragma unroll
    for (int td = 0; td < 2; ++td)
      #pragma unroll
      for (int th = 0; th < 2; ++th)
        #pragma unroll
        for (int e = 0; e < 16; ++e) acc[td][th][e] = 0.f;

    int sj[4];
    #pragma unroll
    for (int j = 0; j < 4; ++j) sj[j] = (2 * dp - 1 + j) & 3;

    #pragma unroll
    for (int kw = 0; kw < 3; ++kw) {
      frag a[4][4];   // [plane j = kd+td][row r = kh+th], rows 2q..2q+3
      #pragma unroll
      for (int j = 0; j < 4; ++j)
        #pragma unroll
        for (int r = 0; r < 4; ++r)
          a[j][r] = *(const frag*)&xlds[((sj[j] * 10 + 2 * q + r) * 34 + kw) * 16 + abase];
      #pragma unroll
      for (int kd = 0; kd < 3; ++kd)
        #pragma unroll
        for (int kh = 0; kh < 3; ++kh) {
          frag b = *(const frag*)&wlds[((kd * 3 + kh) * 3 + kw) * 512 + abase];
          #pragma unroll
          for (int td = 0; td < 2; ++td)
            #pragma unroll
            for (int th = 0; th < 2; ++th)
              acc[td][th] = __builtin_amdgcn_mfma_f32_32x32x16_bf16(
                  a[kd + td][kh + th], b, acc[td][th], 0, 0, 0);
        }
    }

    // pool (2x2x2) + bias + LSE over oc + relu + store
    #pragma unroll
    for (int j = 0; j < 8; ++j) {
      float p0 = fmaxf(fmaxf(acc[0][0][2 * j], acc[0][0][2 * j + 1]),
                       fmaxf(acc[0][1][2 * j], acc[0][1][2 * j + 1]));
      float p1 = fmaxf(fmaxf(acc[1][0][2 * j], acc[1][0][2 * j + 1]),
                       fmaxf(acc[1][1][2 * j], acc[1][1][2 * j + 1]));
      float v = fmaxf(p0, p1) + bv;
      float M = v;
      #pragma unroll
      for (int s = 16; s >= 1; s >>= 1) M = fmaxf(M, __shfl_xor(M, s, 64));
      float S = __expf(v - M);
      #pragma unroll
      for (int s = 16; s >= 1; s >>= 1) S += __shfl_xor(S, s, 64);
      if (m == 0) {
        float r = fmaxf(M + __logf(S), 0.f);
        int pw = 16 * wt + (j & 1) + 4 * (j >> 1) + 2 * hs;
        out[((n * 16 + dp) * 32 + 4 * hpt + q) * 32 + pw] = r;
      }
    }
  }
}

// ---- Fallback (fp32 direct, known-correct) -----------------------------------
__global__ __launch_bounds__(256, 2)
void fused_conv_pool_lse(const float* __restrict__ x,
                         const float* __restrict__ w,
                         const float* __restrict__ bias,
                         float* __restrict__ out) {
  __shared__ float wl[COUT * CIN * 27];
  __shared__ float pl[CIN * 4 * 4 * 18];
  const int tx = threadIdx.x;
  const int oc = tx & 31, wq = tx >> 5;
  const int wtile = blockIdx.x, hp = blockIdx.y, n = blockIdx.z;
  for (int i = tx; i < COUT * CIN * 27; i += 256) {
    int o = i / 432, ick = i - o * 432;
    wl[ick * 32 + o] = w[i];
  }
  const float bv = bias[oc];
  const int h0 = 2 * hp - 1, w0 = 16 * wtile - 1, pwoff = 2 * wq;
  for (int dp = 0; dp < 16; ++dp) {
    const int d0 = 2 * dp - 1;
    __syncthreads();
    for (int i = tx; i < CIN * 4 * 4 * 18; i += 256) {
      int ww = i % 18, t = i / 18;
      int h = t & 3; t >>= 2;
      int d = t & 3, ic = t >> 2;
      int gd = d0 + d, gh = h0 + h, gw = w0 + ww;
      float v = 0.f;
      if ((unsigned)gd < (unsigned)D_ && (unsigned)gh < (unsigned)H_ &&
          (unsigned)gw < (unsigned)W_)
        v = x[(((n * CIN + ic) * D_ + gd) * H_ + gh) * W_ + gw];
      pl[i] = v;
    }
    __syncthreads();
    float acc[2][2][2] = {};
    for (int ic = 0; ic < CIN; ++ic) {
      float rv[4][4][4];
      const float* pb = &pl[ic * 288 + pwoff];
      #pragma unroll
      for (int d = 0; d < 4; ++d)
        #pragma unroll
        for (int h = 0; h < 4; ++h) {
          const float2* p2 = (const float2*)(pb + (d * 4 + h) * 18);
          float2 a = p2[0], b2 = p2[1];
          rv[d][h][0] = a.x; rv[d][h][1] = a.y;
          rv[d][h][2] = b2.x; rv[d][h][3] = b2.y;
        }
      const float* wb = &wl[ic * 27 * 32 + oc];
      #pragma unroll
      for (int kd = 0; kd < 3; ++kd)
        #pragma unroll
        for (int kh = 0; kh < 3; ++kh)
          #pragma unroll
          for (int kw = 0; kw < 3; ++kw) {
            float wv = wb[((kd * 3 + kh) * 3 + kw) * 32];
            #pragma unroll
            for (int pd = 0; pd < 2; ++pd)
              #pragma unroll
              for (int ph = 0; ph < 2; ++ph)
                #pragma unroll
                for (int pw = 0; pw < 2; ++pw)
                  acc[pd][ph][pw] = fmaf(wv, rv[pd + kd][ph + kh][pw + kw], acc[pd][ph][pw]);
          }
    }
    float mx = acc[0][0][0];
    mx = fmaxf(mx, acc[0][0][1]); mx = fmaxf(mx, acc[0][1][0]);
    mx = fmaxf(mx, acc[0][1][1]); mx = fmaxf(mx, acc[1][0][0]);
    mx = fmaxf(mx, acc[1][0][1]); mx = fmaxf(mx, acc[1][1][0]);
    mx = fmaxf(mx, acc[1][1][1]);
    float v = mx + bv;
    float M = v;
    #pragma unroll
    for (int s = 16; s >= 1; s >>= 1) M = fmaxf(M, __shfl_xor(M, s, 64));
    float S = __expf(v - M);
    #pragma unroll
    for (int s = 16; s >= 1; s >>= 1) S += __shfl_xor(S, s, 64);
    if (oc == 0) {
      float r = M + __logf(S);
      out[((n * 16 + dp) * 32 + hp) * 32 + wtile * 8 + wq] = fmaxf(r, 0.f);
    }
  }
}

extern "C" void kernel_launch(void* const* d_in, const int* in_sizes, int n_in,
                              void* d_out, int out_size, void* d_ws, size_t ws_size,
                              hipStream_t stream) {
  const float* x = (const float*)d_in[0];
  const float* w = (const float*)d_in[1];
  const float* b = (const float*)d_in[2];
  float* out = (float*)d_out;
  const size_t nxT = (size_t)N_ * D_ * H_ * W_ * CIN * 2;        // 64 MiB
  const size_t need = nxT + (size_t)27 * 32 * 16 * 2;            // + 54 KiB
  if (ws_size >= need) {
    __hip_bfloat16* xT = (__hip_bfloat16*)d_ws;
    __hip_bfloat16* wT = (__hip_bfloat16*)((char*)d_ws + nxT);
    transpose_x<<<dim3(16384), dim3(256), 0, stream>>>(x, xT);
    prep_w<<<dim3(108), dim3(256), 0, stream>>>(w, wT);
    conv_mfma<<<dim3(2, 8, 32), dim3(256), 0, stream>>>(xT, wT, b, out);
  } else {
    fused_conv_pool_lse<<<dim3(4, 32, 16), dim3(256), 0, stream>>>(x, w, b, out);
  }
}

// Round 4
// 243.614 us; speedup vs baseline: 6.1119x; 1.1051x over previous
//
#include <hip/hip_runtime.h>
#include <hip/hip_bf16.h>
#include <math.h>

#define N_   16
#define CIN  16
#define D_   32
#define H_   64
#define W_   64
#define COUT 32

#define DHW_ (D_ * H_ * W_)
#define HW_  (H_ * W_)

using frag  = __attribute__((ext_vector_type(8))) short;   // 8 bf16 = 4 VGPRs
using v16f  = __attribute__((ext_vector_type(16))) float;  // MFMA 32x32 accum

static __device__ __forceinline__ unsigned short f2bf(float f) {
  union { float f; unsigned u; } a; a.f = f;
  unsigned u = a.u;
  unsigned r = (u + 0x7fffu + ((u >> 16) & 1u)) >> 16;   // RNE
  return (unsigned short)r;
}
static __device__ __forceinline__ unsigned pack2(float lo, float hi) {
  return (unsigned)f2bf(lo) | ((unsigned)f2bf(hi) << 16);
}

// Single fused kernel: conv3d(16->32,k3,p1) + bias + maxpool2^3 + LSE(ch) + relu.
// Block = 4 waves. Grid (wt=2, hpt=8, z=32: n=z>>1, dphalf=z&1).
// xlds: ring of 4 d-planes (slot = plane&3) x 10 h-rows x 34 w x 16 ic, bf16.
// Staging reads fp32 x directly (gather 8 ic per task -> packed ds_write_b128);
// iteration dpi+1's loads are ISSUED before dpi's MFMA block (register
// prefetch), committed to LDS after the post-compute barrier.
__global__ __launch_bounds__(256, 2)
void conv_fused(const float* __restrict__ x,
                const float* __restrict__ w,
                const float* __restrict__ bias,
                float* __restrict__ out) {
  __shared__ __hip_bfloat16 xlds[4 * 10 * 34 * 16];   // 43520 B
  __shared__ __hip_bfloat16 wlds[27 * 32 * 16];       // 27648 B

  const int tid = threadIdx.x;
  const int lane = tid & 63;
  const int q = tid >> 6;            // wave id
  const int m = lane & 31;
  const int hs = lane >> 5;
  const int wt = blockIdx.x;         // 0..1
  const int hpt = blockIdx.y;        // 0..7
  const int n = blockIdx.z >> 1;
  const int dphalf = blockIdx.z & 1;

  // ---- stage weights: wlds[tap][oc][ic] <- bf16(w[oc][ic][tap]) --------------
  for (int i = tid; i < 27 * 32 * 16; i += 256) {
    int ic = i & 15;
    int t2 = i >> 4;
    int oc = t2 & 31;
    int tap = t2 >> 5;
    wlds[i] = __hip_bfloat16(__hip_bfloat16_raw{f2bf(w[(oc * 16 + ic) * 27 + tap])});
  }

  const float bv = bias[m];
  const int abase = m * 16 + hs * 8;
  const int h0 = 8 * hpt - 1;
  const int w0g = wt * 32 - 1;
  const float* xn = x + (size_t)n * CIN * DHW_;

  // Task t in [0,1360) stages one (plane,row,w-slot,ic-half) group of 8 ic.
  // ru = t/68 in [0,20): plane = g0 + (ru>=10), rr = ru%10.
  // sub = t%68: s = sub>>1 in [0,34) (w-slot), half = sub&1 (ic half).
  auto task_decode = [&](int t, int g0, int& g, int& rr, int& s, int& half) {
    int ru = t / 68;
    int sub = t - ru * 68;
    g = g0 + (ru >= 10 ? 1 : 0);
    rr = ru >= 10 ? ru - 10 : ru;
    s = sub >> 1;
    half = sub & 1;
  };

  // Immediate staging of planes {g0, g0+1} (prologue): load+pack+write.
  auto stage_pair_now = [&](int g0) {
    #pragma unroll
    for (int k = 0; k < 6; ++k) {
      int t = tid + 256 * k;
      if (t < 1360) {
        int g, rr, s, half;
        task_decode(t, g0, g, rr, s, half);
        int h = h0 + rr, gw = w0g + s;
        bool v = ((unsigned)g < (unsigned)D_) && ((unsigned)h < (unsigned)H_) &&
                 ((unsigned)gw < (unsigned)W_);
        const float* p = xn + (size_t)(half * 8) * DHW_ + g * HW_ + h * W_ + gw;
        float f[8];
        #pragma unroll
        for (int j = 0; j < 8; ++j) f[j] = v ? p[(size_t)j * DHW_] : 0.f;
        uint4 val;
        val.x = pack2(f[0], f[1]); val.y = pack2(f[2], f[3]);
        val.z = pack2(f[4], f[5]); val.w = pack2(f[6], f[7]);
        *(uint4*)&xlds[(((g & 3) * 10 + rr) * 34 + s) * 16 + half * 8] = val;
      }
    }
  };

  float pf[6][8];   // prefetch buffer, live across the MFMA block

  auto issue = [&](int g0) {
    #pragma unroll
    for (int k = 0; k < 6; ++k) {
      int t = tid + 256 * k;
      int g, rr, s, half;
      task_decode(t, g0, g, rr, s, half);
      int h = h0 + rr, gw = w0g + s;
      bool v = (t < 1360) && ((unsigned)g < (unsigned)D_) &&
               ((unsigned)h < (unsigned)H_) && ((unsigned)gw < (unsigned)W_);
      const float* p = xn + (size_t)(half * 8) * DHW_ + g * HW_ + h * W_ + gw;
      #pragma unroll
      for (int j = 0; j < 8; ++j) pf[k][j] = v ? p[(size_t)j * DHW_] : 0.f;
    }
  };

  auto commit = [&](int g0) {
    #pragma unroll
    for (int k = 0; k < 6; ++k) {
      int t = tid + 256 * k;
      if (t < 1360) {
        int g, rr, s, half;
        task_decode(t, g0, g, rr, s, half);
        uint4 val;
        val.x = pack2(pf[k][0], pf[k][1]); val.y = pack2(pf[k][2], pf[k][3]);
        val.z = pack2(pf[k][4], pf[k][5]); val.w = pack2(pf[k][6], pf[k][7]);
        *(uint4*)&xlds[(((g & 3) * 10 + rr) * 34 + s) * 16 + half * 8] = val;
      }
    }
  };

  const int dp0 = dphalf * 8;
  stage_pair_now(2 * dp0 - 1);
  stage_pair_now(2 * dp0 + 1);
  __syncthreads();   // prologue staging + weights visible

  for (int dpi = 0; dpi < 8; ++dpi) {
    const int dp = dp0 + dpi;

    if (dpi < 7) issue(2 * dp + 3);   // loads in flight during compute

    // ---- MFMA compute (verified R3 structure) --------------------------------
    v16f acc[2][2];
    #pragma unroll
    for (int td = 0; td < 2; ++td)
      #pragma unroll
      for (int th = 0; th < 2; ++th)
        #pragma unroll
        for (int e = 0; e < 16; ++e) acc[td][th][e] = 0.f;

    int sj[4];
    #pragma unroll
    for (int j = 0; j < 4; ++j) sj[j] = (2 * dp - 1 + j) & 3;

    #pragma unroll
    for (int kw = 0; kw < 3; ++kw) {
      frag a[4][4];   // [plane j = kd+td][row r = kh+th], rows 2q..2q+3
      #pragma unroll
      for (int j = 0; j < 4; ++j)
        #pragma unroll
        for (int r = 0; r < 4; ++r)
          a[j][r] = *(const frag*)&xlds[((sj[j] * 10 + 2 * q + r) * 34 + kw) * 16 + abase];
      #pragma unroll
      for (int kd = 0; kd < 3; ++kd)
        #pragma unroll
        for (int kh = 0; kh < 3; ++kh) {
          frag b = *(const frag*)&wlds[((kd * 3 + kh) * 3 + kw) * 512 + abase];
          #pragma unroll
          for (int td = 0; td < 2; ++td)
            #pragma unroll
            for (int th = 0; th < 2; ++th)
              acc[td][th] = __builtin_amdgcn_mfma_f32_32x32x16_bf16(
                  a[kd + td][kh + th], b, acc[td][th], 0, 0, 0);
        }
    }

    // ---- pool (2x2x2) + bias + LSE over oc + relu + store --------------------
    #pragma unroll
    for (int j = 0; j < 8; ++j) {
      float p0 = fmaxf(fmaxf(acc[0][0][2 * j], acc[0][0][2 * j + 1]),
                       fmaxf(acc[0][1][2 * j], acc[0][1][2 * j + 1]));
      float p1 = fmaxf(fmaxf(acc[1][0][2 * j], acc[1][0][2 * j + 1]),
                       fmaxf(acc[1][1][2 * j], acc[1][1][2 * j + 1]));
      float v = fmaxf(p0, p1) + bv;
      float M = v;
      #pragma unroll
      for (int s = 16; s >= 1; s >>= 1) M = fmaxf(M, __shfl_xor(M, s, 64));
      float S = __expf(v - M);
      #pragma unroll
      for (int s = 16; s >= 1; s >>= 1) S += __shfl_xor(S, s, 64);
      if (m == 0) {
        float r = fmaxf(M + __logf(S), 0.f);
        int pw = 16 * wt + (j & 1) + 4 * (j >> 1) + 2 * hs;
        out[((n * 16 + dp) * 32 + 4 * hpt + q) * 32 + pw] = r;
      }
    }

    __syncthreads();   // all waves done reading the slots commit will overwrite
    if (dpi < 7) {
      commit(2 * dp + 3);   // ds_writes only; barrier below drains lgkm, not HBM
      __syncthreads();
    }
  }
}

extern "C" void kernel_launch(void* const* d_in, const int* in_sizes, int n_in,
                              void* d_out, int out_size, void* d_ws, size_t ws_size,
                              hipStream_t stream) {
  const float* x = (const float*)d_in[0];
  const float* w = (const float*)d_in[1];
  const float* b = (const float*)d_in[2];
  float* out = (float*)d_out;
  conv_fused<<<dim3(2, 8, 32), dim3(256), 0, stream>>>(x, w, b, out);
}